// Round 3
// baseline (335.599 us; speedup 1.0000x reference)
//
#include <hip/hip_runtime.h>
#include <hip/hip_bf16.h>

// Constants: M=5,N=2 -> U=3, GROUPS=4, DIL=2, KSIZE=13; B=8, C=O=256, T=16384,
// Ti=8192, BOUNDARY=sqrt(2). Folded form: t0/d2/d1 are each 5-tap convs over
// xs_i[c,m]=x[b,c,2m+i]:
//   t0[t] = mask * (sum_e w0[e]*xs[t-2+e] + bias)        w0[e]=w[.,.,3e]
//   d2[t] = mask * sum_e (w1[e-1]-w1[e])*xs[t-2+e]       w1[j]=w[.,.,3j+1]
//   d1[t] = mask * sum_e (w2[e-1]-w2[e])*xs[t-2+e]       w2[j]=w[.,.,3j+2]
//   den   = clip(t0 - mean5(t0), 1, sqrt(2))
//   out[2t+i] = 0.25*(t0 + (d1+d2)/den + 2*(d2-d1)/den^2),  mask: 2<=t<=8189
//
// R2/R3: swapped-operand MFMA (mfma(x_frag, w_frag)) so C/D rows = t, cols = o.
// Each lane holds 4 consecutive t per u-tile for ONE o -> mean5 is lane-local
// + 4 boundary dwords via shfl (2 shfl + select each). Epilogue LDS buffers,
// 4 barriers, and phase serialization eliminated (1 barrier total, LDS 21.5KB,
// bank conflicts from epilogue gone). Staging bf16 cvt via cvt_pk pairs.
// (R3 = R2 resubmitted after infra-only bench failure; audit found no OOB.)

typedef float v4f __attribute__((ext_vector_type(4)));
typedef short v8s __attribute__((ext_vector_type(8)));

#define TI 8192
#define TFULL 16384
#define TB 64               // stored outputs per phase per block
#define XPH_BYTES 10752     // 84 rows * 128 B (swizzled [t][c] bf16 tile)
#define LDS_BYTES 21504     // 2 phase tiles only

__device__ __forceinline__ unsigned bf16w(float f) {
    unsigned u = __float_as_uint(f);
    return (u + 0x7FFFu + ((u >> 16) & 1u)) >> 16;
}

__device__ __forceinline__ unsigned packbf2(float lo, float hi) {
    union { __hip_bfloat162 h; unsigned u; } cv;
    cv.h = __float22bfloat162_rn(make_float2(lo, hi));   // -> v_cvt_pk_bf16_f32
    return cv.u;
}

// ---------------- prep: fold weights into bf16 fragments ----------------
// ws element layout (ushort): ((((g*5+e)*2+kc)*12+mt)*64+lane)*8+j
// holds W[o][c]: o=16*(mt&3)+(lane&15), c=32*kc+(lane>>4)*8+j, array a=mt>>2.
__global__ void prep_kernel(const float* __restrict__ w, unsigned short* __restrict__ gw) {
    int id = blockIdx.x * 256 + threadIdx.x;   // 245760 total
    int j    = id & 7;
    int lane = (id >> 3) & 63;
    int fid  = id >> 9;
    int mt   = fid % 12;  fid /= 12;
    int kc   = fid & 1;   fid >>= 1;
    int e    = fid % 5;
    int g    = fid / 5;
    int a  = mt >> 2;
    int mg = mt & 3;
    int o  = 16 * mg + (lane & 15);
    int c  = 32 * kc + (lane >> 4) * 8 + j;
    const float* wb = w + (((size_t)(g * 64 + o)) * 64 + c) * 13;
    float val;
    if (a == 0) {
        val = wb[3 * e];
    } else {
        int tap = (a == 1) ? 1 : 2;
        float lo = (e > 0) ? wb[3 * (e - 1) + tap] : 0.0f;
        float hi = (e < 4) ? wb[3 * e + tap] : 0.0f;
        val = lo - hi;
    }
    gw[id] = (unsigned short)bf16w(val);
}

// ---------------- main ----------------
__global__ __launch_bounds__(512, 4)
void pconv_mfma(const unsigned short* __restrict__ gw, const float* __restrict__ x,
                const float* __restrict__ bias, float* __restrict__ out) {
    extern __shared__ char smem[];

    const int tid  = threadIdx.x;
    const int lane = tid & 63;
    const int wv   = tid >> 6;      // 0..7
    const int mg   = wv >> 1;       // o-slice [16mg,16mg+16)
    const int ph   = wv & 1;        // dilation phase
    const int col  = lane & 15;
    const int quad = lane >> 4;

    const int tileIdx = blockIdx.x;       // 0..127
    const int g       = blockIdx.y;       // 0..3
    const int b       = blockIdx.z;       // 0..7
    const int tb      = tileIdx * TB;

    // ---- stage x: de-interleave + transpose + bf16, XOR-swizzled [t][c] ----
    // phase tile p: rows trel in [0,84) <-> m = tb-4+trel; 16B block of 8 ch at
    // byte: p*XPH + trel*128 + ((cblk ^ (trel&7))<<4) + (c&7)*2
    {
        const float* xb = x + ((size_t)(b * 256 + g * 64)) * TFULL;
        const int v0 = 2 * tb - 8;          // 168 values per channel
        for (int f = tid; f < 1344; f += 512) {       // 32 cpairs * 42 vquads
            int q  = f % 42;
            int cp = f / 42;
            int vq = v0 + 4 * q;
            const float* r0 = xb + (size_t)(2 * cp) * TFULL;
            const float* r1 = r0 + TFULL;
            float a0, a1, a2, a3, b0, b1, b2, b3;
            if (vq >= 0 && vq + 3 < TFULL) {
                v4f A4 = *(const v4f*)(r0 + vq);
                v4f B4 = *(const v4f*)(r1 + vq);
                a0 = A4[0]; a1 = A4[1]; a2 = A4[2]; a3 = A4[3];
                b0 = B4[0]; b1 = B4[1]; b2 = B4[2]; b3 = B4[3];
            } else {
                a0 = (vq >= 0 && vq < TFULL) ? r0[vq] : 0.0f;
                a1 = (vq + 1 >= 0 && vq + 1 < TFULL) ? r0[vq + 1] : 0.0f;
                a2 = (vq + 2 >= 0 && vq + 2 < TFULL) ? r0[vq + 2] : 0.0f;
                a3 = (vq + 3 >= 0 && vq + 3 < TFULL) ? r0[vq + 3] : 0.0f;
                b0 = (vq >= 0 && vq < TFULL) ? r1[vq] : 0.0f;
                b1 = (vq + 1 >= 0 && vq + 1 < TFULL) ? r1[vq + 1] : 0.0f;
                b2 = (vq + 2 >= 0 && vq + 2 < TFULL) ? r1[vq + 2] : 0.0f;
                b3 = (vq + 3 >= 0 && vq + 3 < TFULL) ? r1[vq + 3] : 0.0f;
            }
            int cblk = cp >> 2;
            int woff = (cp & 3) * 4;
            unsigned w0 = packbf2(a0, b0);  // p=0, trel=2q   (ch 2cp lo, 2cp+1 hi)
            unsigned w1 = packbf2(a1, b1);  // p=1, trel=2q
            unsigned w2 = packbf2(a2, b2);  // p=0, trel=2q+1
            unsigned w3 = packbf2(a3, b3);  // p=1, trel=2q+1
            int t0r = 2 * q, t1r = 2 * q + 1;
            *(unsigned*)(smem + 0 * XPH_BYTES + t0r * 128 + ((cblk ^ (t0r & 7)) << 4) + woff) = w0;
            *(unsigned*)(smem + 1 * XPH_BYTES + t0r * 128 + ((cblk ^ (t0r & 7)) << 4) + woff) = w1;
            *(unsigned*)(smem + 0 * XPH_BYTES + t1r * 128 + ((cblk ^ (t1r & 7)) << 4) + woff) = w2;
            *(unsigned*)(smem + 1 * XPH_BYTES + t1r * 128 + ((cblk ^ (t1r & 7)) << 4) + woff) = w3;
        }
    }
    __syncthreads();

    // ---- K-loop: 10 ksteps (5 taps x 2 kchunks), 15 MFMAs each ----
    // SWAPPED operands: D = Xfrag * Wfrag -> rows = t (idx=16u+4quad+reg),
    // cols = o (16mg+col).
    const unsigned short* gwp = gw + (size_t)g * 61440;
    v4f acc[3][5];
    #pragma unroll
    for (int a = 0; a < 3; ++a)
        #pragma unroll
        for (int u = 0; u < 5; ++u) acc[a][u] = (v4f){0.f, 0.f, 0.f, 0.f};

    const char* xph = smem + ph * XPH_BYTES;
    #pragma unroll
    for (int e = 0; e < 5; ++e) {
        #pragma unroll
        for (int kc = 0; kc < 2; ++kc) {
            v8s Af[3];
            #pragma unroll
            for (int a = 0; a < 3; ++a)
                Af[a] = *(const v8s*)(gwp + (((e * 2 + kc) * 12 + 4 * a + mg) << 9) + (lane << 3));
            // X addr: xrel = 16u+col+e; block-swizzle sel = (col+e)&7
            const int sw = (col + e) * 128 + (((4 * kc + quad) ^ ((col + e) & 7)) << 4);
            #pragma unroll
            for (int u = 0; u < 5; ++u) {
                v8s Bf = *(const v8s*)(xph + u * 2048 + sw);
                #pragma unroll
                for (int a = 0; a < 3; ++a)
                    acc[a][u] = __builtin_amdgcn_mfma_f32_16x16x32_bf16(Bf, Af[a], acc[a][u], 0, 0, 0);
            }
        }
    }
    // no barrier: LDS is read-only from here and never reused

    // ---- register epilogue ----
    // lane owns o = g*64+16mg+col; t idx = 16u+4quad+reg, t = tb-2+idx.
    const int oG = g * 64 + 16 * mg + col;
    const float bias_s = bias[oG];
    float* ob = out + ((size_t)(b * 256 + oG)) * TFULL;
    const bool edge = (tileIdx == 0) || (tileIdx == 127);

    // pass 1: bias + mask in place
    #pragma unroll
    for (int u = 0; u < 5; ++u) {
        v4f t0v = acc[0][u];
        #pragma unroll
        for (int r = 0; r < 4; ++r) t0v[r] += bias_s;
        if (edge) {
            v4f d2v = acc[1][u];
            v4f d1v = acc[2][u];
            #pragma unroll
            for (int r = 0; r < 4; ++r) {
                int t = tb - 2 + 16 * u + 4 * quad + r;
                if (t < 2 || t > TI - 3) { t0v[r] = 0.f; d2v[r] = 0.f; d1v[r] = 0.f; }
            }
            acc[1][u] = d2v;
            acc[2][u] = d1v;
        }
        acc[0][u] = t0v;
    }

    // pass 2: mean5 via lane-local window + shfl boundaries, combine, store
    const int tlb = (lane + 48) & 63;   // lane-16 (quad-1; quad0 -> quad3)
    const int tla = (lane + 16) & 63;   // lane+16 (quad+1; quad3 -> quad0)
    #pragma unroll
    for (int u = 0; u < 5; ++u) {
        const v4f Tm = acc[0][u];
        const v4f Tp = acc[0][u > 0 ? u - 1 : 0];   // dummy at u=0 (unused lanes)
        const v4f Tn = acc[0][u < 4 ? u + 1 : 4];   // dummy at u=4 (unused lanes)
        float b2o = __shfl(Tm[2], tlb), b2s = __shfl(Tp[2], tlb);
        float b1o = __shfl(Tm[3], tlb), b1s = __shfl(Tp[3], tlb);
        float a0o = __shfl(Tm[0], tla), a0s = __shfl(Tn[0], tla);
        float a1o = __shfl(Tm[1], tla), a1s = __shfl(Tn[1], tla);
        float wn[8];
        wn[0] = (quad == 0) ? b2s : b2o;   // idx - 2
        wn[1] = (quad == 0) ? b1s : b1o;   // idx - 1
        wn[2] = Tm[0]; wn[3] = Tm[1]; wn[4] = Tm[2]; wn[5] = Tm[3];
        wn[6] = (quad == 3) ? a0s : a0o;   // idx + 4
        wn[7] = (quad == 3) ? a1s : a1o;   // idx + 5
        #pragma unroll
        for (int r = 0; r < 4; ++r) {
            float t0 = wn[r + 2];
            float m5 = 0.2f * (wn[r] + wn[r + 1] + wn[r + 2] + wn[r + 3] + wn[r + 4]);
            float den = fminf(fmaxf(t0 - m5, 1.0f), 1.41421356237309515f);
            float rc = 1.0f / den;
            float d2 = acc[1][u][r];
            float d1 = acc[2][u][r];
            float res = 0.25f * (t0 + (d1 + d2) * rc + 2.0f * (d2 - d1) * rc * rc);
            int j = 16 * u + 4 * quad + r - 2;      // output t = tb + j
            if (u == 0) {
                if (j >= 0) ob[2 * (tb + j) + ph] = res;
            } else if (u == 4) {
                if (j < TB) ob[2 * (tb + j) + ph] = res;
            } else {
                ob[2 * (tb + j) + ph] = res;
            }
        }
    }
}

extern "C" void kernel_launch(void* const* d_in, const int* in_sizes, int n_in,
                              void* d_out, int out_size, void* d_ws, size_t ws_size,
                              hipStream_t stream) {
    const float* x  = (const float*)d_in[0];  // (8, 256, 16384) f32
    const float* w  = (const float*)d_in[1];  // (256, 64, 13)   f32
    const float* bb = (const float*)d_in[2];  // (256,)          f32
    float* out = (float*)d_out;

    unsigned short* gw = (unsigned short*)d_ws;   // 245760 ushort = 491520 B

    prep_kernel<<<960, 256, 0, stream>>>(w, gw);
    pconv_mfma<<<dim3(128, 4, 8), 512, LDS_BYTES, stream>>>(gw, x, bb, out);
}

// Round 4
// 299.821 us; speedup vs baseline: 1.1193x; 1.1193x over previous
//
#include <hip/hip_runtime.h>
#include <hip/hip_bf16.h>

// Constants: M=5,N=2 -> U=3, GROUPS=4, DIL=2, KSIZE=13; B=8, C=O=256, T=16384,
// Ti=8192, BOUNDARY=sqrt(2). Folded form: t0/d2/d1 are each 5-tap convs over
// xs_i[c,m]=x[b,c,2m+i]:
//   t0[t] = mask * (sum_e w0[e]*xs[t-2+e] + bias)        w0[e]=w[.,.,3e]
//   d2[t] = mask * sum_e (w1[e-1]-w1[e])*xs[t-2+e]       w1[j]=w[.,.,3j+1]
//   d1[t] = mask * sum_e (w2[e-1]-w2[e])*xs[t-2+e]       w2[j]=w[.,.,3j+2]
//   den   = clip(t0 - mean5(t0), 1, sqrt(2))
//   out[2t+i] = 0.25*(t0 + (d1+d2)/den + 2*(d2-d1)/den^2),  mask: 2<=t<=8189
//
// R4: R3's swapped-MFMA register mean5 kept, but final stores routed through a
// compact LDS transpose res[2][64][65] f32 (33.3KB, aliased over x tile).
// R3's register-direct stores were 64x4B scatter per instruction (16 o-rows x
// 4 t per inst) -> ~1280 write txn/wave, stalling the memory pipe. Now: store
// pass pairs both phases per lane -> dense 512B/inst, 8 insts/wave (~32 txn).
// LDS 33,280B -> 4 blocks/CU capacity; VGPR kept <=64 for 8 waves/SIMD.

typedef float v4f __attribute__((ext_vector_type(4)));
typedef short v8s __attribute__((ext_vector_type(8)));

#define TI 8192
#define TFULL 16384
#define TB 64               // stored outputs per phase per block
#define XPH_BYTES 10752     // 84 rows * 128 B (swizzled [t][c] bf16 tile)
#define RES_S 65            // res row stride (floats), odd => conflict-free
#define LDS_BYTES 33280     // 2*64*65*4 res buffer (x tile aliased below it)

__device__ __forceinline__ unsigned bf16w(float f) {
    unsigned u = __float_as_uint(f);
    return (u + 0x7FFFu + ((u >> 16) & 1u)) >> 16;
}

__device__ __forceinline__ unsigned packbf2(float lo, float hi) {
    union { __hip_bfloat162 h; unsigned u; } cv;
    cv.h = __float22bfloat162_rn(make_float2(lo, hi));   // -> v_cvt_pk_bf16_f32
    return cv.u;
}

// ---------------- prep: fold weights into bf16 fragments ----------------
// ws element layout (ushort): ((((g*5+e)*2+kc)*12+mt)*64+lane)*8+j
// holds W[o][c]: o=16*(mt&3)+(lane&15), c=32*kc+(lane>>4)*8+j, array a=mt>>2.
__global__ void prep_kernel(const float* __restrict__ w, unsigned short* __restrict__ gw) {
    int id = blockIdx.x * 256 + threadIdx.x;   // 245760 total
    int j    = id & 7;
    int lane = (id >> 3) & 63;
    int fid  = id >> 9;
    int mt   = fid % 12;  fid /= 12;
    int kc   = fid & 1;   fid >>= 1;
    int e    = fid % 5;
    int g    = fid / 5;
    int a  = mt >> 2;
    int mg = mt & 3;
    int o  = 16 * mg + (lane & 15);
    int c  = 32 * kc + (lane >> 4) * 8 + j;
    const float* wb = w + (((size_t)(g * 64 + o)) * 64 + c) * 13;
    float val;
    if (a == 0) {
        val = wb[3 * e];
    } else {
        int tap = (a == 1) ? 1 : 2;
        float lo = (e > 0) ? wb[3 * (e - 1) + tap] : 0.0f;
        float hi = (e < 4) ? wb[3 * e + tap] : 0.0f;
        val = lo - hi;
    }
    gw[id] = (unsigned short)bf16w(val);
}

// ---------------- main ----------------
__global__ __launch_bounds__(512, 4)
void pconv_mfma(const unsigned short* __restrict__ gw, const float* __restrict__ x,
                const float* __restrict__ bias, float* __restrict__ out) {
    extern __shared__ char smem[];
    float* smemf = (float*)smem;

    const int tid  = threadIdx.x;
    const int lane = tid & 63;
    const int wv   = tid >> 6;      // 0..7
    const int mg   = wv >> 1;       // o-slice [16mg,16mg+16)
    const int ph   = wv & 1;        // dilation phase
    const int col  = lane & 15;
    const int quad = lane >> 4;

    const int tileIdx = blockIdx.x;       // 0..127
    const int g       = blockIdx.y;       // 0..3
    const int b       = blockIdx.z;       // 0..7
    const int tb      = tileIdx * TB;

    // ---- stage x: de-interleave + transpose + bf16, XOR-swizzled [t][c] ----
    // phase tile p: rows trel in [0,84) <-> m = tb-4+trel; 16B block of 8 ch at
    // byte: p*XPH + trel*128 + ((cblk ^ (trel&7))<<4) + (c&7)*2
    {
        const float* xb = x + ((size_t)(b * 256 + g * 64)) * TFULL;
        const int v0 = 2 * tb - 8;          // 168 values per channel
        for (int f = tid; f < 1344; f += 512) {       // 32 cpairs * 42 vquads
            int q  = f % 42;
            int cp = f / 42;
            int vq = v0 + 4 * q;
            const float* r0 = xb + (size_t)(2 * cp) * TFULL;
            const float* r1 = r0 + TFULL;
            float a0, a1, a2, a3, b0, b1, b2, b3;
            if (vq >= 0 && vq + 3 < TFULL) {
                v4f A4 = *(const v4f*)(r0 + vq);
                v4f B4 = *(const v4f*)(r1 + vq);
                a0 = A4[0]; a1 = A4[1]; a2 = A4[2]; a3 = A4[3];
                b0 = B4[0]; b1 = B4[1]; b2 = B4[2]; b3 = B4[3];
            } else {
                a0 = (vq >= 0 && vq < TFULL) ? r0[vq] : 0.0f;
                a1 = (vq + 1 >= 0 && vq + 1 < TFULL) ? r0[vq + 1] : 0.0f;
                a2 = (vq + 2 >= 0 && vq + 2 < TFULL) ? r0[vq + 2] : 0.0f;
                a3 = (vq + 3 >= 0 && vq + 3 < TFULL) ? r0[vq + 3] : 0.0f;
                b0 = (vq >= 0 && vq < TFULL) ? r1[vq] : 0.0f;
                b1 = (vq + 1 >= 0 && vq + 1 < TFULL) ? r1[vq + 1] : 0.0f;
                b2 = (vq + 2 >= 0 && vq + 2 < TFULL) ? r1[vq + 2] : 0.0f;
                b3 = (vq + 3 >= 0 && vq + 3 < TFULL) ? r1[vq + 3] : 0.0f;
            }
            int cblk = cp >> 2;
            int woff = (cp & 3) * 4;
            unsigned w0 = packbf2(a0, b0);  // p=0, trel=2q   (ch 2cp lo, 2cp+1 hi)
            unsigned w1 = packbf2(a1, b1);  // p=1, trel=2q
            unsigned w2 = packbf2(a2, b2);  // p=0, trel=2q+1
            unsigned w3 = packbf2(a3, b3);  // p=1, trel=2q+1
            int t0r = 2 * q, t1r = 2 * q + 1;
            *(unsigned*)(smem + 0 * XPH_BYTES + t0r * 128 + ((cblk ^ (t0r & 7)) << 4) + woff) = w0;
            *(unsigned*)(smem + 1 * XPH_BYTES + t0r * 128 + ((cblk ^ (t0r & 7)) << 4) + woff) = w1;
            *(unsigned*)(smem + 0 * XPH_BYTES + t1r * 128 + ((cblk ^ (t1r & 7)) << 4) + woff) = w2;
            *(unsigned*)(smem + 1 * XPH_BYTES + t1r * 128 + ((cblk ^ (t1r & 7)) << 4) + woff) = w3;
        }
    }
    __syncthreads();

    // ---- K-loop: 10 ksteps (5 taps x 2 kchunks), 15 MFMAs each ----
    // SWAPPED operands: D = Xfrag * Wfrag -> rows = t (idx=16u+4quad+reg),
    // cols = o (16mg+col).
    const unsigned short* gwp = gw + (size_t)g * 61440;
    v4f acc[3][5];
    #pragma unroll
    for (int a = 0; a < 3; ++a)
        #pragma unroll
        for (int u = 0; u < 5; ++u) acc[a][u] = (v4f){0.f, 0.f, 0.f, 0.f};

    const char* xph = smem + ph * XPH_BYTES;
    #pragma unroll
    for (int e = 0; e < 5; ++e) {
        #pragma unroll
        for (int kc = 0; kc < 2; ++kc) {
            v8s Af[3];
            #pragma unroll
            for (int a = 0; a < 3; ++a)
                Af[a] = *(const v8s*)(gwp + (((e * 2 + kc) * 12 + 4 * a + mg) << 9) + (lane << 3));
            // X addr: xrel = 16u+col+e; block-swizzle sel = (col+e)&7
            const int sw = (col + e) * 128 + (((4 * kc + quad) ^ ((col + e) & 7)) << 4);
            #pragma unroll
            for (int u = 0; u < 5; ++u) {
                v8s Bf = *(const v8s*)(xph + u * 2048 + sw);
                #pragma unroll
                for (int a = 0; a < 3; ++a)
                    acc[a][u] = __builtin_amdgcn_mfma_f32_16x16x32_bf16(Bf, Af[a], acc[a][u], 0, 0, 0);
            }
        }
    }

    // ---- register epilogue (mean5 in-lane), results -> LDS transpose ----
    // lane owns o_local = 16mg+col; t idx = 16u+4quad+reg, t = tb-2+idx.
    const int oL = 16 * mg + col;
    const float bias_s = bias[g * 64 + oL];
    const bool edge = (tileIdx == 0) || (tileIdx == 127);

    // pass 1: bias + mask in place
    #pragma unroll
    for (int u = 0; u < 5; ++u) {
        v4f t0v = acc[0][u];
        #pragma unroll
        for (int r = 0; r < 4; ++r) t0v[r] += bias_s;
        if (edge) {
            v4f d2v = acc[1][u];
            v4f d1v = acc[2][u];
            #pragma unroll
            for (int r = 0; r < 4; ++r) {
                int t = tb - 2 + 16 * u + 4 * quad + r;
                if (t < 2 || t > TI - 3) { t0v[r] = 0.f; d2v[r] = 0.f; d1v[r] = 0.f; }
            }
            acc[1][u] = d2v;
            acc[2][u] = d1v;
        }
        acc[0][u] = t0v;
    }

    __syncthreads();   // all K-loop LDS reads done; res buffer aliases x tile

    // pass 2: mean5 via lane-local window + shfl boundaries, res -> LDS
    float* resp = smemf + ph * (64 * RES_S);
    const int tlb = (lane + 48) & 63;   // lane-16 (quad-1; quad0 -> quad3)
    const int tla = (lane + 16) & 63;   // lane+16 (quad+1; quad3 -> quad0)
    #pragma unroll
    for (int u = 0; u < 5; ++u) {
        const v4f Tm = acc[0][u];
        const v4f Tp = acc[0][u > 0 ? u - 1 : 0];   // dummy at u=0 (unused lanes)
        const v4f Tn = acc[0][u < 4 ? u + 1 : 4];   // dummy at u=4 (unused lanes)
        float b2o = __shfl(Tm[2], tlb), b2s = __shfl(Tp[2], tlb);
        float b1o = __shfl(Tm[3], tlb), b1s = __shfl(Tp[3], tlb);
        float a0o = __shfl(Tm[0], tla), a0s = __shfl(Tn[0], tla);
        float a1o = __shfl(Tm[1], tla), a1s = __shfl(Tn[1], tla);
        float wn[8];
        wn[0] = (quad == 0) ? b2s : b2o;   // idx - 2
        wn[1] = (quad == 0) ? b1s : b1o;   // idx - 1
        wn[2] = Tm[0]; wn[3] = Tm[1]; wn[4] = Tm[2]; wn[5] = Tm[3];
        wn[6] = (quad == 3) ? a0s : a0o;   // idx + 4
        wn[7] = (quad == 3) ? a1s : a1o;   // idx + 5
        #pragma unroll
        for (int r = 0; r < 4; ++r) {
            float t0 = wn[r + 2];
            float m5 = 0.2f * (wn[r] + wn[r + 1] + wn[r + 2] + wn[r + 3] + wn[r + 4]);
            float den = fminf(fmaxf(t0 - m5, 1.0f), 1.41421356237309515f);
            float rc = 1.0f / den;
            float d2 = acc[1][u][r];
            float d1 = acc[2][u][r];
            float res = 0.25f * (t0 + (d1 + d2) * rc + 2.0f * (d2 - d1) * rc * rc);
            int j = 16 * u + 4 * quad + r - 2;      // output t = tb + j
            if (j >= 0 && j < TB) resp[oL * RES_S + j] = res;
        }
    }
    __syncthreads();

    // ---- dense store: lane = j, float2 pairs both phases (k=2j+ph) ----
    const float* r0b = smemf;                   // phase 0: res[o][j]
    const float* r1b = smemf + 64 * RES_S;      // phase 1
    float* obase = out + ((size_t)(b * 256 + g * 64)) * TFULL;
    #pragma unroll
    for (int i = 0; i < 8; ++i) {
        int o = 8 * wv + i;
        float2 v;
        v.x = r0b[o * RES_S + lane];
        v.y = r1b[o * RES_S + lane];
        *(float2*)(obase + (size_t)o * TFULL + 2 * (tb + lane)) = v;
    }
}

extern "C" void kernel_launch(void* const* d_in, const int* in_sizes, int n_in,
                              void* d_out, int out_size, void* d_ws, size_t ws_size,
                              hipStream_t stream) {
    const float* x  = (const float*)d_in[0];  // (8, 256, 16384) f32
    const float* w  = (const float*)d_in[1];  // (256, 64, 13)   f32
    const float* bb = (const float*)d_in[2];  // (256,)          f32
    float* out = (float*)d_out;

    unsigned short* gw = (unsigned short*)d_ws;   // 245760 ushort = 491520 B

    prep_kernel<<<960, 256, 0, stream>>>(w, gw);
    pconv_mfma<<<dim3(128, 4, 8), 512, LDS_BYTES, stream>>>(gw, x, bb, out);
}